// Round 7
// baseline (648.807 us; speedup 1.0000x reference)
//
#include <hip/hip_runtime.h>
#include <hip/hip_bf16.h>

#define B_ 4
#define L_ 2052
#define C_ 1024
#define H_ 16
#define D_ 64
#define NREG_ 4
#define M_ (B_*L_)     // 8208
#define MP_ 8320       // M padded to x128 for unguarded global_load_lds staging
#define LPV_ 2112      // Vt padded col count (33 x 64-key tiles, zero-filled tail)
#define QSC 0.18033688f  // 0.125 * log2(e), applied in fp32 inside attn

typedef short bf16x8 __attribute__((ext_vector_type(8)));
typedef float f32x4 __attribute__((ext_vector_type(4)));
typedef __hip_bfloat16 bf16;

#define MFMA(a,b,c) __builtin_amdgcn_mfma_f32_16x16x32_bf16(a,b,c,0,0,0)

typedef __attribute__((address_space(3))) unsigned int  lds_u32;
typedef const __attribute__((address_space(1))) unsigned int glb_u32;

__device__ inline void load_lds16(const bf16* g, bf16* l){
    __builtin_amdgcn_global_load_lds((glb_u32*)g, (lds_u32*)l, 16, 0, 0);
}

__device__ inline float b2f(bf16 v){ return __bfloat162float(v); }
__device__ inline bf16  f2b(float v){ return __float2bfloat16(v); }

// ---------------- x -> bf16 hi/lo split ----------------
__global__ __launch_bounds__(256)
void cvt_split(const float* __restrict__ in, bf16* __restrict__ hi,
               bf16* __restrict__ lo, int n)
{
    int i = (blockIdx.x*256 + threadIdx.x)*4;
    if (i >= n) return;
    float4 v = *(const float4*)(in + i);
    int2 hraw, lraw;
    bf16* hp = (bf16*)&hraw;
    bf16* lp = (bf16*)&lraw;
    float vv[4] = {v.x, v.y, v.z, v.w};
    #pragma unroll
    for (int j=0;j<4;++j){
        bf16 h = f2b(vv[j]);
        hp[j] = h;
        lp[j] = f2b(vv[j] - b2f(h));
    }
    *(int2*)(hi + i) = hraw;
    *(int2*)(lo + i) = lraw;
}

// ---------------- fp32 [R][Cc] -> bf16 transposed [Cc][R] ----------------
__global__ __launch_bounds__(256)
void transpose_cvt(const float* __restrict__ in, bf16* __restrict__ out,
                   int R, int Cc)
{
    __shared__ bf16 t[32][33];
    int bx = blockIdx.x * 32;
    int by = blockIdx.y * 32;
    int tx = threadIdx.x;
    int ty = threadIdx.y;
    #pragma unroll
    for (int i=0;i<4;++i){
        int r = by + ty + i*8;
        int c = bx + tx;
        t[ty+i*8][tx] = f2b(in[(size_t)r*Cc + c]);
    }
    __syncthreads();
    #pragma unroll
    for (int i=0;i<4;++i){
        int r = bx + ty + i*8;
        int c = by + tx;
        out[(size_t)r*R + c] = t[tx][ty+i*8];
    }
}

// ---- GEMM via global_load_lds staging ----
template<typename OutT, bool SPLIT>
__global__ __launch_bounds__(256)
void gemm_lds(const bf16* __restrict__ A, const bf16* __restrict__ Alo,
              const bf16* __restrict__ Bt, const float* __restrict__ bias,
              OutT* __restrict__ C, int M, int N, int K)
{
    __shared__ bf16 As[128*32];
    __shared__ bf16 Als[SPLIT ? 128*32 : 8];
    __shared__ bf16 Bs[128*32];

    int tid  = threadIdx.x;
    int lane = tid & 63, wave = tid >> 6;
    int wm = (wave>>1)*64, wn = (wave&1)*64;
    int bm = blockIdx.y*128, bn = blockIdx.x*128;
    int lrow = lane & 15, lk8 = (lane>>4)*8;
    int quad = lane >> 4;

    f32x4 acc[4][4] = {};

    int lin0 = tid, lin1 = tid + 256;
    int r0 = lin0 >> 2, c0 = (lin0 & 3)*8;
    int r1 = lin1 >> 2, c1 = (lin1 & 3)*8;
    const size_t a0 = (size_t)(bm + r0)*K + c0;
    const size_t a1 = (size_t)(bm + r1)*K + c1;
    const size_t b0 = (size_t)(bn + r0)*K + c0;
    const size_t b1 = (size_t)(bn + r1)*K + c1;

    for (int k0 = 0; k0 < K; k0 += 32) {
        load_lds16(A + a0 + k0, &As[lin0*8]);
        load_lds16(A + a1 + k0, &As[lin1*8]);
        if constexpr (SPLIT) {
            load_lds16(Alo + a0 + k0, &Als[lin0*8]);
            load_lds16(Alo + a1 + k0, &Als[lin1*8]);
        }
        load_lds16(Bt + b0 + k0, &Bs[lin0*8]);
        load_lds16(Bt + b1 + k0, &Bs[lin1*8]);
        __syncthreads();

        bf16x8 a[4], al[4], b[4];
        #pragma unroll
        for (int i=0;i<4;++i){
            a[i] = *(const bf16x8*)(&As[(wm+i*16+lrow)*32 + lk8]);
            if constexpr (SPLIT)
                al[i] = *(const bf16x8*)(&Als[(wm+i*16+lrow)*32 + lk8]);
            b[i] = *(const bf16x8*)(&Bs[(wn+i*16+lrow)*32 + lk8]);
        }
        #pragma unroll
        for (int mi=0;mi<4;++mi)
            #pragma unroll
            for (int ni=0;ni<4;++ni){
                acc[mi][ni] = MFMA(a[mi], b[ni], acc[mi][ni]);
                if constexpr (SPLIT)
                    acc[mi][ni] = MFMA(al[mi], b[ni], acc[mi][ni]);
            }
        __syncthreads();
    }

    #pragma unroll
    for (int ni=0;ni<4;++ni){
        int col = bn + wn + ni*16 + lrow;
        float bv = bias[col];
        #pragma unroll
        for (int mi=0;mi<4;++mi){
            int rowb = bm + wm + mi*16 + quad*4;
            #pragma unroll
            for (int r=0;r<4;++r){
                int row = rowb + r;
                if (row < M) {
                    float v = acc[mi][ni][r] + bv;
                    if constexpr (sizeof(OutT)==4) C[(size_t)row*N + col] = v;
                    else                           C[(size_t)row*N + col] = f2b(v);
                }
            }
        }
    }
}

// ---------------- RoPE in-place on q,k (pure rotation) ----------------
__global__ __launch_bounds__(256)
void rope_kernel(bf16* __restrict__ qkv, const float* __restrict__ rope)
{
    int idx = blockIdx.x*256 + threadIdx.x;
    int d = idx & 31;
    int h = (idx >> 5) & 15;
    int m = idx >> 9;
    if (m >= M_) return;
    int l = m % L_;
    if (l < NREG_) return;
    const float* cp = rope + (size_t)(l - NREG_)*D_;
    const float* sp = rope + (size_t)(L_ - NREG_)*D_ + (size_t)(l - NREG_)*D_;
    float c0 = cp[d], c1 = cp[d+32], s0 = sp[d], s1 = sp[d+32];
    size_t base = (size_t)m*3072 + h*64;
    {
        float a = b2f(qkv[base + d]), b = b2f(qkv[base + d + 32]);
        qkv[base + d]      = f2b(a*c0 - b*s0);
        qkv[base + d + 32] = f2b(b*c1 + a*s1);
    }
    {
        size_t kb = base + 1024;
        float a = b2f(qkv[kb + d]), b = b2f(qkv[kb + d + 32]);
        qkv[kb + d]      = f2b(a*c0 - b*s0);
        qkv[kb + d + 32] = f2b(b*c1 + a*s1);
    }
}

// ---------------- V -> Vt [B*H][D][LPV_] (zero-padded tail cols) ----------------
__global__ __launch_bounds__(256)
void transpose_v(const bf16* __restrict__ qkv, bf16* __restrict__ Vt)
{
    __shared__ bf16 t[64*72];
    int bh = blockIdx.y, lt = blockIdx.x;
    int b = bh >> 4, h = bh & 15;
    int tid = threadIdx.x;
    #pragma unroll
    for (int it=0; it<2; ++it){
        int i = tid + it*256;
        int il = i >> 3, c = (i&7)*8;
        int l = lt*64 + il;
        int4 v = {0,0,0,0};
        if (l < L_) v = *(const int4*)(qkv + ((size_t)b*L_ + l)*3072 + 2048 + h*64 + c);
        *(int4*)(&t[il*72 + c]) = v;
    }
    __syncthreads();
    #pragma unroll
    for (int it=0; it<2; ++it){
        int i = tid + it*256;
        int d = i >> 3, ck = (i&7)*8;
        union { int4 q; bf16 e[8]; } u;
        #pragma unroll
        for (int j=0;j<8;++j) u.e[j] = t[(ck+j)*72 + d];
        *(int4*)(&Vt[((size_t)bh*64 + d)*LPV_ + lt*64 + ck]) = u.q;
    }
}

// ---------------- flash attention: barrier-free, direct-global fragments ----------------
// grid: (ceil(L/128), B*H), block 256 (4 waves, 32 Q-rows each).
// S^T = K*Q^T so P lands key-contiguous per lane -> packed b64 LDS writes,
// b128 A-layout reads. LDS = wave-private P only; NO __syncthreads.
__global__ __launch_bounds__(256)
void attn_kernel(const bf16* __restrict__ qkv, const bf16* __restrict__ Vt,
                 float* __restrict__ out)
{
    __shared__ bf16 sP[4*32*72];   // per-wave P: [32 q][72 key-stride]

    int tid = threadIdx.x, lane = tid & 63, wave = tid >> 6;
    int lrow = lane & 15, quad = lane >> 4;
    int qt = blockIdx.x, bh = blockIdx.y;
    int b  = bh >> 4, h = bh & 15;
    size_t rowbase = (size_t)b * L_;
    int q0 = qt*128 + wave*32;

    bf16* pw = &sP[wave*2304];

    // Q fragments (B-operand: n=q-row=lrow, k=d=s*32+quad*8+j), loaded once
    bf16x8 qf[2][2];
    #pragma unroll
    for (int qi=0;qi<2;++qi)
        #pragma unroll
        for (int s=0;s<2;++s)
            qf[qi][s] = *(const bf16x8*)(qkv + (rowbase + q0 + qi*16 + lrow)*3072
                                         + h*64 + s*32 + quad*8);

    float lst[2] = {0.f, 0.f};
    f32x4 o_[2][4] = {};

    const bf16* kb = qkv + (rowbase + lrow)*3072 + 1024 + h*64 + quad*8;
    const bf16* vb = Vt + ((size_t)bh*64 + lrow)*LPV_ + quad*8;

    for (int kt = 0; kt < 33; ++kt) {
        // K fragments (A-operand: m=key=lrow, k=d) — direct global, coalesced b128
        bf16x8 kf[4][2];
        #pragma unroll
        for (int ki=0;ki<4;++ki)
            #pragma unroll
            for (int s=0;s<2;++s)
                kf[ki][s] = *(const bf16x8*)(kb + (size_t)(kt*64 + ki*16)*3072 + s*32);
        // V fragments (B-operand: n=d=lrow, k=key) — direct global, coalesced b128
        bf16x8 vf[4][2];
        #pragma unroll
        for (int ni=0;ni<4;++ni)
            #pragma unroll
            for (int s=0;s<2;++s)
                vf[ni][s] = *(const bf16x8*)(vb + ni*16*LPV_ + kt*64 + s*32);

        bool full = (kt != 32);
        #pragma unroll
        for (int ki=0;ki<4;++ki){
            #pragma unroll
            for (int qi=0;qi<2;++qi){
                f32x4 t = {};
                t = MFMA(kf[ki][0], qf[qi][0], t);   // S^T: rows=key, cols=q
                t = MFMA(kf[ki][1], qf[qi][1], t);
                union { int2 d2; bf16 e[4]; } u;
                #pragma unroll
                for (int r=0;r<4;++r){
                    float e = __builtin_amdgcn_exp2f(t[r]*QSC);
                    float p = (full || (2048 + ki*16 + quad*4 + r) < L_) ? e : 0.f;
                    lst[qi] += p;
                    u.e[r] = f2b(p);
                }
                // P[q][key]: lane's 4 values are key-contiguous -> one b64 write
                *(int2*)(&pw[(qi*16 + lrow)*72 + ki*16 + quad*4]) = u.d2;
            }
        }

        // P in A-layout (m=q=lrow, k=key=s*32+quad*8+j): b128 reads (wave-private,
        // lgkmcnt-ordered; no barrier needed)
        bf16x8 pf[2][2];
        #pragma unroll
        for (int mi=0;mi<2;++mi)
            #pragma unroll
            for (int s=0;s<2;++s)
                pf[mi][s] = *(const bf16x8*)(&pw[(mi*16 + lrow)*72 + s*32 + quad*8]);
        #pragma unroll
        for (int mi=0;mi<2;++mi)
            #pragma unroll
            for (int ni=0;ni<4;++ni){
                f32x4 t = o_[mi][ni];
                t = MFMA(pf[mi][0], vf[ni][0], t);
                t = MFMA(pf[mi][1], vf[ni][1], t);
                o_[mi][ni] = t;
            }
    }

    // lst held per q-row at lane&15; sum across quads
    #pragma unroll
    for (int qi=0;qi<2;++qi){
        lst[qi] += __shfl_xor(lst[qi], 16);
        lst[qi] += __shfl_xor(lst[qi], 32);
    }

    // O C-layout: rows q=quad*4+r, cols d=lrow. Pull row sums via shfl.
    #pragma unroll
    for (int mi=0;mi<2;++mi)
        #pragma unroll
        for (int r=0;r<4;++r){
            float sum = __shfl(lst[mi], quad*4 + r);
            float inv = 1.f / sum;
            int lq = q0 + mi*16 + quad*4 + r;
            if (lq < L_){
                size_t base = (rowbase + lq)*1024 + h*64;
                #pragma unroll
                for (int ni=0;ni<4;++ni)
                    out[base + ni*16 + lrow] = o_[mi][ni][r]*inv;
            }
        }
}

// ---------------- LayerNorm (fp32 in) -> bf16 hi/lo split ----------------
__global__ __launch_bounds__(256)
void ln_kernel(const float* __restrict__ in, const float* __restrict__ gamma,
               const float* __restrict__ beta, bf16* __restrict__ yhi,
               bf16* __restrict__ ylo)
{
    int row = blockIdx.x;
    int tid = threadIdx.x;
    int wave = tid >> 6, lane = tid & 63;
    float4 v4 = *(const float4*)(in + (size_t)row*1024 + tid*4);
    float v[4] = {v4.x, v4.y, v4.z, v4.w};
    float s = 0.f, q = 0.f;
    #pragma unroll
    for (int j=0;j<4;++j){ s += v[j]; q += v[j]*v[j]; }
    #pragma unroll
    for (int o=1;o<64;o<<=1){ s += __shfl_xor(s, o); q += __shfl_xor(q, o); }
    __shared__ float sh[8];
    if (lane == 0){ sh[wave] = s; sh[4+wave] = q; }
    __syncthreads();
    s = sh[0]+sh[1]+sh[2]+sh[3];
    q = sh[4]+sh[5]+sh[6]+sh[7];
    float mu  = s * (1.f/1024.f);
    float var = q * (1.f/1024.f) - mu*mu;
    float rstd = rsqrtf(var + 1e-5f);
    int2 hraw, lraw;
    bf16* hb = (bf16*)&hraw;
    bf16* lb = (bf16*)&lraw;
    #pragma unroll
    for (int j=0;j<4;++j){
        float g = gamma[tid*4+j], be = beta[tid*4+j];
        float y = (v[j]-mu)*rstd*g + be;
        bf16 hh = f2b(y);
        hb[j] = hh;
        lb[j] = f2b(y - b2f(hh));
    }
    *(int2*)(yhi + (size_t)row*1024 + tid*4) = hraw;
    *(int2*)(ylo + (size_t)row*1024 + tid*4) = lraw;
}

// ---------------- launch ----------------
extern "C" void kernel_launch(void* const* d_in, const int* in_sizes, int n_in,
                              void* d_out, int out_size, void* d_ws, size_t ws_size,
                              hipStream_t stream)
{
    const float* x     = (const float*)d_in[0];
    const float* rope  = (const float*)d_in[1];
    const float* Wqkv  = (const float*)d_in[2];
    const float* bqkv  = (const float*)d_in[3];
    const float* Wproj = (const float*)d_in[4];
    const float* bproj = (const float*)d_in[5];
    const float* lng   = (const float*)d_in[6];
    const float* lnb   = (const float*)d_in[7];
    float* out = (float*)d_out;

    char* ws = (char*)d_ws;
    size_t off = 0;
    auto alloc = [&](size_t bytes)->char* {
        char* p = ws + off;
        off += (bytes + 255) & ~(size_t)255;
        return p;
    };
    bf16* xhi    = (bf16*)alloc((size_t)MP_*C_*2);
    bf16* xlo    = (bf16*)alloc((size_t)MP_*C_*2);
    bf16* WqkvT  = (bf16*)alloc((size_t)3*C_*C_*2);
    bf16* WprojT = (bf16*)alloc((size_t)C_*C_*2);
    bf16* qkv    = (bf16*)alloc((size_t)M_*3*C_*2);
    bf16* Vt     = (bf16*)alloc((size_t)B_*H_*D_*LPV_*2);
    bf16* yhi    = (bf16*)alloc((size_t)MP_*C_*2);
    bf16* ylo    = (bf16*)alloc((size_t)MP_*C_*2);

    float* attnF = (float*)xhi;        // xhi+xlo = 2*MP_*C_*2 >= M_*C_*4 bytes

    cvt_split<<<M_*C_/1024, 256, 0, stream>>>(x, xhi, xlo, M_*C_);
    transpose_cvt<<<dim3(3*C_/32, C_/32), dim3(32,8), 0, stream>>>(Wqkv, WqkvT, C_, 3*C_);
    transpose_cvt<<<dim3(C_/32, C_/32), dim3(32,8), 0, stream>>>(Wproj, WprojT, C_, C_);
    gemm_lds<bf16, true><<<dim3(3*C_/128, MP_/128), 256, 0, stream>>>(
        xhi, xlo, WqkvT, bqkv, qkv, M_, 3*C_, C_);
    rope_kernel<<<(M_*H_*32)/256, 256, 0, stream>>>(qkv, rope);
    transpose_v<<<dim3(LPV_/64, B_*H_), 256, 0, stream>>>(qkv, Vt);
    attn_kernel<<<dim3((L_+127)/128, B_*H_), 256, 0, stream>>>(qkv, Vt, attnF);
    ln_kernel<<<M_, 256, 0, stream>>>(attnF, lng, lnb, yhi, ylo);
    gemm_lds<float, true><<<dim3(C_/128, MP_/128), 256, 0, stream>>>(
        yhi, ylo, WprojT, bproj, out, M_, C_, C_);
}

// Round 8
// 490.636 us; speedup vs baseline: 1.3224x; 1.3224x over previous
//
#include <hip/hip_runtime.h>
#include <hip/hip_bf16.h>

#define B_ 4
#define L_ 2052
#define C_ 1024
#define H_ 16
#define D_ 64
#define NREG_ 4
#define M_ (B_*L_)     // 8208
#define LP_ 2056       // padded L stride for Vt (16B-aligned rows)
#define QSC 0.18033688f  // 0.125 * log2(e), applied in fp32 inside attn

typedef short bf16x8 __attribute__((ext_vector_type(8)));
typedef float f32x4 __attribute__((ext_vector_type(4)));
typedef __hip_bfloat16 bf16;

#define MFMA(a,b,c) __builtin_amdgcn_mfma_f32_16x16x32_bf16(a,b,c,0,0,0)

__device__ inline float b2f(bf16 v){ return __bfloat162float(v); }
__device__ inline bf16  f2b(float v){ return __float2bfloat16(v); }

// ---------------- x -> bf16 hi/lo split ----------------
__global__ __launch_bounds__(256)
void cvt_split(const float* __restrict__ in, bf16* __restrict__ hi,
               bf16* __restrict__ lo, int n)
{
    int i = (blockIdx.x*256 + threadIdx.x)*4;
    if (i >= n) return;
    float4 v = *(const float4*)(in + i);
    int2 hraw, lraw;
    bf16* hp = (bf16*)&hraw;
    bf16* lp = (bf16*)&lraw;
    float vv[4] = {v.x, v.y, v.z, v.w};
    #pragma unroll
    for (int j=0;j<4;++j){
        bf16 h = f2b(vv[j]);
        hp[j] = h;
        lp[j] = f2b(vv[j] - b2f(h));
    }
    *(int2*)(hi + i) = hraw;
    *(int2*)(lo + i) = lraw;
}

// ---------------- fp32 [R][Cc] -> bf16 transposed [Cc][R] ----------------
__global__ __launch_bounds__(256)
void transpose_cvt(const float* __restrict__ in, bf16* __restrict__ out,
                   int R, int Cc)
{
    __shared__ bf16 t[32][33];
    int bx = blockIdx.x * 32;
    int by = blockIdx.y * 32;
    int tx = threadIdx.x;
    int ty = threadIdx.y;
    #pragma unroll
    for (int i=0;i<4;++i){
        int r = by + ty + i*8;
        int c = bx + tx;
        t[ty+i*8][tx] = f2b(in[(size_t)r*Cc + c]);
    }
    __syncthreads();
    #pragma unroll
    for (int i=0;i<4;++i){
        int r = bx + ty + i*8;
        int c = by + tx;
        out[(size_t)r*R + c] = t[tx][ty+i*8];
    }
}

// ---------------- GEMM: A[M][K] (+optional lo) x Bt[N][K] -> C[M][N] ----------------
template<typename OutT, bool SPLIT>
__global__ __launch_bounds__(256)
void gemm_bt(const bf16* __restrict__ A, const bf16* __restrict__ Alo,
             const bf16* __restrict__ Bt, const float* __restrict__ bias,
             OutT* __restrict__ C, int M, int N, int K)
{
    __shared__ bf16 As[128*40];
    __shared__ bf16 Als[SPLIT ? 128*40 : 8];
    __shared__ bf16 Bs[128*40];

    int tid  = threadIdx.x;
    int lane = tid & 63, wave = tid >> 6;
    int wm = (wave>>1)*64, wn = (wave&1)*64;
    int bm = blockIdx.y*128, bn = blockIdx.x*128;
    int lrow = lane & 15, lk8 = (lane>>4)*8;
    int quad = lane >> 4;

    f32x4 acc[4][4] = {};

    int r0 = tid >> 2;
    int c0 = (tid & 3) * 8;

    for (int k0 = 0; k0 < K; k0 += 32) {
        #pragma unroll
        for (int it=0; it<2; ++it) {
            int r = r0 + it*64;
            int ga = bm + r;
            int4 va = {0,0,0,0}, vl = {0,0,0,0}, vb = {0,0,0,0};
            if (ga < M) {
                va = *(const int4*)(A + (size_t)ga*K + k0 + c0);
                if constexpr (SPLIT)
                    vl = *(const int4*)(Alo + (size_t)ga*K + k0 + c0);
            }
            int gb = bn + r;
            if (gb < N) vb = *(const int4*)(Bt + (size_t)gb*K + k0 + c0);
            *(int4*)(&As[r*40 + c0]) = va;
            if constexpr (SPLIT) *(int4*)(&Als[r*40 + c0]) = vl;
            *(int4*)(&Bs[r*40 + c0]) = vb;
        }
        __syncthreads();
        bf16x8 a[4], al[4], b[4];
        #pragma unroll
        for (int i=0;i<4;++i){
            a[i] = *(const bf16x8*)(&As[(wm+i*16+lrow)*40 + lk8]);
            if constexpr (SPLIT)
                al[i] = *(const bf16x8*)(&Als[(wm+i*16+lrow)*40 + lk8]);
            b[i] = *(const bf16x8*)(&Bs[(wn+i*16+lrow)*40 + lk8]);
        }
        #pragma unroll
        for (int mi=0;mi<4;++mi)
            #pragma unroll
            for (int ni=0;ni<4;++ni){
                acc[mi][ni] = MFMA(a[mi], b[ni], acc[mi][ni]);
                if constexpr (SPLIT)
                    acc[mi][ni] = MFMA(al[mi], b[ni], acc[mi][ni]);
            }
        __syncthreads();
    }

    #pragma unroll
    for (int ni=0;ni<4;++ni){
        int col = bn + wn + ni*16 + lrow;
        float bv = bias[col];
        #pragma unroll
        for (int mi=0;mi<4;++mi){
            int rowb = bm + wm + mi*16 + quad*4;
            #pragma unroll
            for (int r=0;r<4;++r){
                int row = rowb + r;
                if (row < M) {
                    float v = acc[mi][ni][r] + bv;
                    if constexpr (sizeof(OutT)==4) C[(size_t)row*N + col] = v;
                    else                           C[(size_t)row*N + col] = f2b(v);
                }
            }
        }
    }
}

// ---------------- RoPE in-place on q,k (pure rotation) ----------------
__global__ __launch_bounds__(256)
void rope_kernel(bf16* __restrict__ qkv, const float* __restrict__ rope)
{
    int idx = blockIdx.x*256 + threadIdx.x;
    int d = idx & 31;
    int h = (idx >> 5) & 15;
    int m = idx >> 9;
    if (m >= M_) return;
    int l = m % L_;
    if (l < NREG_) return;
    const float* cp = rope + (size_t)(l - NREG_)*D_;
    const float* sp = rope + (size_t)(L_ - NREG_)*D_ + (size_t)(l - NREG_)*D_;
    float c0 = cp[d], c1 = cp[d+32], s0 = sp[d], s1 = sp[d+32];
    size_t base = (size_t)m*3072 + h*64;
    {
        float a = b2f(qkv[base + d]), b = b2f(qkv[base + d + 32]);
        qkv[base + d]      = f2b(a*c0 - b*s0);
        qkv[base + d + 32] = f2b(b*c1 + a*s1);
    }
    {
        size_t kb = base + 1024;
        float a = b2f(qkv[kb + d]), b = b2f(qkv[kb + d + 32]);
        qkv[kb + d]      = f2b(a*c0 - b*s0);
        qkv[kb + d + 32] = f2b(b*c1 + a*s1);
    }
}

// ---------------- V -> Vt [B*H][D][LP_] (zero-padded cols) ----------------
__global__ __launch_bounds__(256)
void transpose_v(const bf16* __restrict__ qkv, bf16* __restrict__ Vt)
{
    __shared__ bf16 t[64*72];
    int bh = blockIdx.y, lt = blockIdx.x;
    int b = bh >> 4, h = bh & 15;
    int tid = threadIdx.x;
    #pragma unroll
    for (int it=0; it<2; ++it){
        int i = tid + it*256;
        int il = i >> 3, c = (i&7)*8;
        int l = lt*64 + il;
        int4 v = {0,0,0,0};
        if (l < L_) v = *(const int4*)(qkv + ((size_t)b*L_ + l)*3072 + 2048 + h*64 + c);
        *(int4*)(&t[il*72 + c]) = v;
    }
    __syncthreads();
    #pragma unroll
    for (int it=0; it<2; ++it){
        int i = tid + it*256;
        int d = i >> 3, ck = (i&7)*8;
        if (lt*64 + ck + 8 <= LP_){
            union { int4 q; bf16 e[8]; } u;
            #pragma unroll
            for (int j=0;j<8;++j) u.e[j] = t[(ck+j)*72 + d];
            *(int4*)(&Vt[((size_t)bh*64 + d)*LP_ + lt*64 + ck]) = u.q;
        }
    }
}

// ---------------- flash attention (round-5 staging + S^T packed-P) ----------------
// grid: (ceil(L/128), B*H), block 256 (4 waves, 32 Q-rows each)
__global__ __launch_bounds__(256)
void attn_kernel(const bf16* __restrict__ qkv, const bf16* __restrict__ Vt,
                 float* __restrict__ out)
{
    __shared__ bf16 sQP[10752];   // Q tile [128][72]; P: 4 waves x [32][72] (stride 2688)
    __shared__ bf16 sK[64*72];    // [key][d]
    __shared__ bf16 sV[64*72];    // [d][key]

    int tid = threadIdx.x, lane = tid & 63, wave = tid >> 6;
    int lrow = lane & 15, lk8 = (lane>>4)*8, quad = lane >> 4;
    int qt = blockIdx.x, bh = blockIdx.y;
    int b  = bh >> 4, h = bh & 15;
    size_t rowbase = (size_t)b * L_;
    int q0 = qt * 128;

    // stage Q tile
    #pragma unroll
    for (int it=0; it<4; ++it){
        int i = tid + it*256;
        int r = i >> 3;
        int c = (i & 7) * 8;
        int lq = q0 + r;
        int4 v = {0,0,0,0};
        if (lq < L_) v = *(const int4*)(qkv + (rowbase + lq)*3072 + h*64 + c);
        *(int4*)(&sQP[r*72 + c]) = v;
    }
    __syncthreads();

    // Q fragments (B-operand for S^T: n=q, k=d)
    bf16x8 qf[2][2];
    #pragma unroll
    for (int qi=0;qi<2;++qi)
        #pragma unroll
        for (int s=0;s<2;++s)
            qf[qi][s] = *(const bf16x8*)(&sQP[(wave*32 + qi*16 + lrow)*72 + s*32 + lk8]);

    float lst[2] = {0.f, 0.f};
    f32x4 o_[2][4] = {};

    bf16* pw = &sQP[wave*2688];   // per-wave P buffer [32][72]
    const int nkt = (L_ + 63) / 64;   // 33

    // prefetch tile 0 into registers
    int4 kr[2], vr[2];
    {
        #pragma unroll
        for (int it=0; it<2; ++it){
            int i = tid + it*256;
            int r = i >> 3, c = (i & 7)*8;
            int lk = r;
            kr[it] = (lk < L_) ? *(const int4*)(qkv + (rowbase+lk)*3072 + 1024 + h*64 + c)
                               : (int4){0,0,0,0};
            vr[it] = *(const int4*)(Vt + ((size_t)bh*64 + r)*LP_ + c);
        }
    }

    for (int kt = 0; kt < nkt; ++kt) {
        __syncthreads();   // LDS free (prev readers done)
        #pragma unroll
        for (int it=0; it<2; ++it){
            int i = tid + it*256;
            int r = i >> 3, c = (i & 7)*8;
            *(int4*)(&sK[r*72 + c]) = kr[it];
            *(int4*)(&sV[r*72 + c]) = vr[it];
        }
        __syncthreads();
        // prefetch next tile (overlaps with compute below)
        if (kt+1 < nkt){
            #pragma unroll
            for (int it=0; it<2; ++it){
                int i = tid + it*256;
                int r = i >> 3, c = (i & 7)*8;
                int lk = (kt+1)*64 + r;
                kr[it] = (lk < L_) ? *(const int4*)(qkv + (rowbase+lk)*3072 + 1024 + h*64 + c)
                                   : (int4){0,0,0,0};
                int vc = (kt+1)*64 + c;
                vr[it] = (vc + 8 <= LP_) ? *(const int4*)(Vt + ((size_t)bh*64 + r)*LP_ + vc)
                                         : (int4){0,0,0,0};
            }
        }

        // S^T = K Q^T (rows=key, cols=q) -> P packed b64 writes, key-contiguous
        bool full = (kt != 32);
        {
            bf16x8 kf[4][2];
            #pragma unroll
            for (int ki=0;ki<4;++ki)
                #pragma unroll
                for (int s=0;s<2;++s)
                    kf[ki][s] = *(const bf16x8*)(&sK[(ki*16+lrow)*72 + s*32 + lk8]);
            #pragma unroll
            for (int ki=0;ki<4;++ki){
                #pragma unroll
                for (int qi=0;qi<2;++qi){
                    f32x4 t = {};
                    t = MFMA(kf[ki][0], qf[qi][0], t);
                    t = MFMA(kf[ki][1], qf[qi][1], t);
                    float p[4];
                    #pragma unroll
                    for (int r=0;r<4;++r){
                        float e = __builtin_amdgcn_exp2f(t[r]*QSC);
                        p[r] = (full || (2048 + ki*16 + quad*4 + r) < L_) ? e : 0.f;
                        lst[qi] += p[r];
                    }
                    union { int2 d2; __hip_bfloat162 h2[2]; } u;
                    u.h2[0] = __float22bfloat162_rn({p[0], p[1]});
                    u.h2[1] = __float22bfloat162_rn({p[2], p[3]});
                    *(int2*)(&pw[(qi*16 + lrow)*72 + ki*16 + quad*4]) = u.d2;
                }
            }
        }

        // O += P V : P in A-layout (m=q, k=key) via b128 reads; V from sV [d][key]
        bf16x8 vf[4][2];
        #pragma unroll
        for (int ni=0;ni<4;++ni)
            #pragma unroll
            for (int s=0;s<2;++s)
                vf[ni][s] = *(const bf16x8*)(&sV[(ni*16+lrow)*72 + s*32 + lk8]);
        bf16x8 pf[2][2];
        #pragma unroll
        for (int mi=0;mi<2;++mi)
            #pragma unroll
            for (int s=0;s<2;++s)
                pf[mi][s] = *(const bf16x8*)(&pw[(mi*16 + lrow)*72 + s*32 + quad*8]);
        #pragma unroll
        for (int mi=0;mi<2;++mi)
            #pragma unroll
            for (int ni=0;ni<4;++ni){
                f32x4 t = o_[mi][ni];
                t = MFMA(pf[mi][0], vf[ni][0], t);
                t = MFMA(pf[mi][1], vf[ni][1], t);
                o_[mi][ni] = t;
            }
    }

    // lst: per-lane partial for q=lrow; sum across quads
    #pragma unroll
    for (int qi=0;qi<2;++qi){
        lst[qi] += __shfl_xor(lst[qi], 16);
        lst[qi] += __shfl_xor(lst[qi], 32);
    }

    // O C-layout: rows q=quad*4+r, cols d=lrow; fetch row sum from lane (quad*4+r)
    #pragma unroll
    for (int mi=0;mi<2;++mi)
        #pragma unroll
        for (int r=0;r<4;++r){
            float sum = __shfl(lst[mi], quad*4 + r);
            float inv = 1.f / sum;
            int lq = q0 + wave*32 + mi*16 + quad*4 + r;
            if (lq < L_){
                size_t base = (rowbase + lq)*1024 + h*64;
                #pragma unroll
                for (int ni=0;ni<4;++ni)
                    out[base + ni*16 + lrow] = o_[mi][ni][r]*inv;
            }
        }
}

// ---------------- LayerNorm (fp32 in) -> bf16 hi/lo split ----------------
__global__ __launch_bounds__(256)
void ln_kernel(const float* __restrict__ in, const float* __restrict__ gamma,
               const float* __restrict__ beta, bf16* __restrict__ yhi,
               bf16* __restrict__ ylo)
{
    int row = blockIdx.x;
    int tid = threadIdx.x;
    int wave = tid >> 6, lane = tid & 63;
    float4 v4 = *(const float4*)(in + (size_t)row*1024 + tid*4);
    float v[4] = {v4.x, v4.y, v4.z, v4.w};
    float s = 0.f, q = 0.f;
    #pragma unroll
    for (int j=0;j<4;++j){ s += v[j]; q += v[j]*v[j]; }
    #pragma unroll
    for (int o=1;o<64;o<<=1){ s += __shfl_xor(s, o); q += __shfl_xor(q, o); }
    __shared__ float sh[8];
    if (lane == 0){ sh[wave] = s; sh[4+wave] = q; }
    __syncthreads();
    s = sh[0]+sh[1]+sh[2]+sh[3];
    q = sh[4]+sh[5]+sh[6]+sh[7];
    float mu  = s * (1.f/1024.f);
    float var = q * (1.f/1024.f) - mu*mu;
    float rstd = rsqrtf(var + 1e-5f);
    int2 hraw, lraw;
    bf16* hb = (bf16*)&hraw;
    bf16* lb = (bf16*)&lraw;
    #pragma unroll
    for (int j=0;j<4;++j){
        float g = gamma[tid*4+j], be = beta[tid*4+j];
        float y = (v[j]-mu)*rstd*g + be;
        bf16 hh = f2b(y);
        hb[j] = hh;
        lb[j] = f2b(y - b2f(hh));
    }
    *(int2*)(yhi + (size_t)row*1024 + tid*4) = hraw;
    *(int2*)(ylo + (size_t)row*1024 + tid*4) = lraw;
}

// ---------------- launch ----------------
extern "C" void kernel_launch(void* const* d_in, const int* in_sizes, int n_in,
                              void* d_out, int out_size, void* d_ws, size_t ws_size,
                              hipStream_t stream)
{
    const float* x     = (const float*)d_in[0];
    const float* rope  = (const float*)d_in[1];
    const float* Wqkv  = (const float*)d_in[2];
    const float* bqkv  = (const float*)d_in[3];
    const float* Wproj = (const float*)d_in[4];
    const float* bproj = (const float*)d_in[5];
    const float* lng   = (const float*)d_in[6];
    const float* lnb   = (const float*)d_in[7];
    float* out = (float*)d_out;

    char* ws = (char*)d_ws;
    size_t off = 0;
    auto alloc = [&](size_t bytes)->char* {
        char* p = ws + off;
        off += (bytes + 255) & ~(size_t)255;
        return p;
    };
    bf16* xhi    = (bf16*)alloc((size_t)M_*C_*2);
    bf16* xlo    = (bf16*)alloc((size_t)M_*C_*2);
    bf16* WqkvT  = (bf16*)alloc((size_t)3*C_*C_*2);
    bf16* WprojT = (bf16*)alloc((size_t)C_*C_*2);
    bf16* qkv    = (bf16*)alloc((size_t)M_*3*C_*2);
    bf16* Vt     = (bf16*)alloc((size_t)B_*H_*D_*LP_*2);

    float* attnF = (float*)xhi;        // xhi+xlo region = exactly M*C*4 bytes
    bf16*  yhi   = qkv;                // qkv dead after attention
    bf16*  ylo   = qkv + (size_t)M_*C_;

    cvt_split<<<M_*C_/1024, 256, 0, stream>>>(x, xhi, xlo, M_*C_);
    transpose_cvt<<<dim3(3*C_/32, C_/32), dim3(32,8), 0, stream>>>(Wqkv, WqkvT, C_, 3*C_);
    transpose_cvt<<<dim3(C_/32, C_/32), dim3(32,8), 0, stream>>>(Wproj, WprojT, C_, C_);
    gemm_bt<bf16, true><<<dim3(3*C_/128, (M_+127)/128), 256, 0, stream>>>(
        xhi, xlo, WqkvT, bqkv, qkv, M_, 3*C_, C_);
    rope_kernel<<<(M_*H_*32)/256, 256, 0, stream>>>(qkv, rope);
    transpose_v<<<dim3((L_+63)/64, B_*H_), 256, 0, stream>>>(qkv, Vt);
    attn_kernel<<<dim3((L_+127)/128, B_*H_), 256, 0, stream>>>(qkv, Vt, attnF);
    ln_kernel<<<M_, 256, 0, stream>>>(attnF, lng, lnb, yhi, ylo);
    gemm_bt<float, true><<<dim3(C_/128, (M_+127)/128), 256, 0, stream>>>(
        yhi, ylo, WprojT, bproj, out, M_, C_, C_);
}

// Round 9
// 474.274 us; speedup vs baseline: 1.3680x; 1.0345x over previous
//
#include <hip/hip_runtime.h>
#include <hip/hip_bf16.h>

#define B_ 4
#define L_ 2052
#define C_ 1024
#define H_ 16
#define D_ 64
#define NREG_ 4
#define M_ (B_*L_)     // 8208
#define LP_ 2056       // padded L stride for Vt (16B-aligned rows)
#define QSC 0.18033688f  // 0.125 * log2(e), applied in fp32 inside attn

typedef short bf16x8 __attribute__((ext_vector_type(8)));
typedef float f32x4 __attribute__((ext_vector_type(4)));
typedef __hip_bfloat16 bf16;

#define MFMA(a,b,c) __builtin_amdgcn_mfma_f32_16x16x32_bf16(a,b,c,0,0,0)

__device__ inline float b2f(bf16 v){ return __bfloat162float(v); }
__device__ inline bf16  f2b(float v){ return __float2bfloat16(v); }

// ---------------- x -> bf16 hi/lo split ----------------
__global__ __launch_bounds__(256)
void cvt_split(const float* __restrict__ in, bf16* __restrict__ hi,
               bf16* __restrict__ lo, int n)
{
    int i = (blockIdx.x*256 + threadIdx.x)*4;
    if (i >= n) return;
    float4 v = *(const float4*)(in + i);
    int2 hraw, lraw;
    bf16* hp = (bf16*)&hraw;
    bf16* lp = (bf16*)&lraw;
    float vv[4] = {v.x, v.y, v.z, v.w};
    #pragma unroll
    for (int j=0;j<4;++j){
        bf16 h = f2b(vv[j]);
        hp[j] = h;
        lp[j] = f2b(vv[j] - b2f(h));
    }
    *(int2*)(hi + i) = hraw;
    *(int2*)(lo + i) = lraw;
}

// ---------------- fp32 [R][Cc] -> bf16 transposed [Cc][R] ----------------
__global__ __launch_bounds__(256)
void transpose_cvt(const float* __restrict__ in, bf16* __restrict__ out,
                   int R, int Cc)
{
    __shared__ bf16 t[32][33];
    int bx = blockIdx.x * 32;
    int by = blockIdx.y * 32;
    int tx = threadIdx.x;
    int ty = threadIdx.y;
    #pragma unroll
    for (int i=0;i<4;++i){
        int r = by + ty + i*8;
        int c = bx + tx;
        t[ty+i*8][tx] = f2b(in[(size_t)r*Cc + c]);
    }
    __syncthreads();
    #pragma unroll
    for (int i=0;i<4;++i){
        int r = bx + ty + i*8;
        int c = by + tx;
        out[(size_t)r*R + c] = t[tx][ty+i*8];
    }
}

// ---- GEMM, block tile 128x256, wave tile 64x128 (mi4 x ni8) ----
// A[M][K] (+optional lo) x Bt[N][K] -> C[M][N] + bias. N%256==0, K%32==0.
template<typename OutT, bool SPLIT>
__global__ __launch_bounds__(256,2)
void gemm_wide(const bf16* __restrict__ A, const bf16* __restrict__ Alo,
               const bf16* __restrict__ Bt, const float* __restrict__ bias,
               OutT* __restrict__ C, int M, int N, int K)
{
    __shared__ bf16 As[128*40];
    __shared__ bf16 Als[SPLIT ? 128*40 : 8];
    __shared__ bf16 Bs[256*40];

    int tid  = threadIdx.x;
    int lane = tid & 63, wave = tid >> 6;
    int wm = (wave>>1)*64, wn = (wave&1)*128;
    int bm = blockIdx.y*128, bn = blockIdx.x*256;
    int lrow = lane & 15, lk8 = (lane>>4)*8;
    int quad = lane >> 4;

    f32x4 acc[4][8] = {};

    int r0 = tid >> 2;          // 0..63
    int c0 = (tid & 3) * 8;     // 0,8,16,24

    for (int k0 = 0; k0 < K; k0 += 32) {
        #pragma unroll
        for (int it=0; it<2; ++it) {
            int r = r0 + it*64;
            int ga = bm + r;
            int4 va = {0,0,0,0}, vl = {0,0,0,0};
            if (ga < M) {
                va = *(const int4*)(A + (size_t)ga*K + k0 + c0);
                if constexpr (SPLIT)
                    vl = *(const int4*)(Alo + (size_t)ga*K + k0 + c0);
            }
            *(int4*)(&As[r*40 + c0]) = va;
            if constexpr (SPLIT) *(int4*)(&Als[r*40 + c0]) = vl;
        }
        #pragma unroll
        for (int it=0; it<4; ++it) {
            int r = r0 + it*64;
            int4 vb = *(const int4*)(Bt + (size_t)(bn + r)*K + k0 + c0);
            *(int4*)(&Bs[r*40 + c0]) = vb;
        }
        __syncthreads();

        bf16x8 b[8];
        #pragma unroll
        for (int i=0;i<8;++i)
            b[i] = *(const bf16x8*)(&Bs[(wn+i*16+lrow)*40 + lk8]);
        #pragma unroll
        for (int mi=0;mi<4;++mi){
            bf16x8 a = *(const bf16x8*)(&As[(wm+mi*16+lrow)*40 + lk8]);
            #pragma unroll
            for (int ni=0;ni<8;++ni)
                acc[mi][ni] = MFMA(a, b[ni], acc[mi][ni]);
            if constexpr (SPLIT) {
                bf16x8 al = *(const bf16x8*)(&Als[(wm+mi*16+lrow)*40 + lk8]);
                #pragma unroll
                for (int ni=0;ni<8;++ni)
                    acc[mi][ni] = MFMA(al, b[ni], acc[mi][ni]);
            }
        }
        __syncthreads();
    }

    #pragma unroll
    for (int ni=0;ni<8;++ni){
        int col = bn + wn + ni*16 + lrow;
        float bv = bias[col];
        #pragma unroll
        for (int mi=0;mi<4;++mi){
            int rowb = bm + wm + mi*16 + quad*4;
            #pragma unroll
            for (int r=0;r<4;++r){
                int row = rowb + r;
                if (row < M) {
                    float v = acc[mi][ni][r] + bv;
                    if constexpr (sizeof(OutT)==4) C[(size_t)row*N + col] = v;
                    else                           C[(size_t)row*N + col] = f2b(v);
                }
            }
        }
    }
}

// ---------------- RoPE in-place on q,k (pure rotation) ----------------
__global__ __launch_bounds__(256)
void rope_kernel(bf16* __restrict__ qkv, const float* __restrict__ rope)
{
    int idx = blockIdx.x*256 + threadIdx.x;
    int d = idx & 31;
    int h = (idx >> 5) & 15;
    int m = idx >> 9;
    if (m >= M_) return;
    int l = m % L_;
    if (l < NREG_) return;
    const float* cp = rope + (size_t)(l - NREG_)*D_;
    const float* sp = rope + (size_t)(L_ - NREG_)*D_ + (size_t)(l - NREG_)*D_;
    float c0 = cp[d], c1 = cp[d+32], s0 = sp[d], s1 = sp[d+32];
    size_t base = (size_t)m*3072 + h*64;
    {
        float a = b2f(qkv[base + d]), b = b2f(qkv[base + d + 32]);
        qkv[base + d]      = f2b(a*c0 - b*s0);
        qkv[base + d + 32] = f2b(b*c1 + a*s1);
    }
    {
        size_t kb = base + 1024;
        float a = b2f(qkv[kb + d]), b = b2f(qkv[kb + d + 32]);
        qkv[kb + d]      = f2b(a*c0 - b*s0);
        qkv[kb + d + 32] = f2b(b*c1 + a*s1);
    }
}

// ---------------- V -> Vt [B*H][D][LP_] (zero-padded cols) ----------------
__global__ __launch_bounds__(256)
void transpose_v(const bf16* __restrict__ qkv, bf16* __restrict__ Vt)
{
    __shared__ bf16 t[64*72];
    int bh = blockIdx.y, lt = blockIdx.x;
    int b = bh >> 4, h = bh & 15;
    int tid = threadIdx.x;
    #pragma unroll
    for (int it=0; it<2; ++it){
        int i = tid + it*256;
        int il = i >> 3, c = (i&7)*8;
        int l = lt*64 + il;
        int4 v = {0,0,0,0};
        if (l < L_) v = *(const int4*)(qkv + ((size_t)b*L_ + l)*3072 + 2048 + h*64 + c);
        *(int4*)(&t[il*72 + c]) = v;
    }
    __syncthreads();
    #pragma unroll
    for (int it=0; it<2; ++it){
        int i = tid + it*256;
        int d = i >> 3, ck = (i&7)*8;
        if (lt*64 + ck + 8 <= LP_){
            union { int4 q; bf16 e[8]; } u;
            #pragma unroll
            for (int j=0;j<8;++j) u.e[j] = t[(ck+j)*72 + d];
            *(int4*)(&Vt[((size_t)bh*64 + d)*LP_ + lt*64 + ck]) = u.q;
        }
    }
}

// ---------------- flash attention (round-8: staging + S^T packed-P) ----------------
__global__ __launch_bounds__(256)
void attn_kernel(const bf16* __restrict__ qkv, const bf16* __restrict__ Vt,
                 float* __restrict__ out)
{
    __shared__ bf16 sQP[10752];   // Q tile [128][72]; P: 4 waves x [32][72] (stride 2688)
    __shared__ bf16 sK[64*72];    // [key][d]
    __shared__ bf16 sV[64*72];    // [d][key]

    int tid = threadIdx.x, lane = tid & 63, wave = tid >> 6;
    int lrow = lane & 15, lk8 = (lane>>4)*8, quad = lane >> 4;
    int qt = blockIdx.x, bh = blockIdx.y;
    int b  = bh >> 4, h = bh & 15;
    size_t rowbase = (size_t)b * L_;
    int q0 = qt * 128;

    #pragma unroll
    for (int it=0; it<4; ++it){
        int i = tid + it*256;
        int r = i >> 3;
        int c = (i & 7) * 8;
        int lq = q0 + r;
        int4 v = {0,0,0,0};
        if (lq < L_) v = *(const int4*)(qkv + (rowbase + lq)*3072 + h*64 + c);
        *(int4*)(&sQP[r*72 + c]) = v;
    }
    __syncthreads();

    bf16x8 qf[2][2];
    #pragma unroll
    for (int qi=0;qi<2;++qi)
        #pragma unroll
        for (int s=0;s<2;++s)
            qf[qi][s] = *(const bf16x8*)(&sQP[(wave*32 + qi*16 + lrow)*72 + s*32 + lk8]);

    float lst[2] = {0.f, 0.f};
    f32x4 o_[2][4] = {};

    bf16* pw = &sQP[wave*2688];
    const int nkt = (L_ + 63) / 64;   // 33

    int4 kr[2], vr[2];
    {
        #pragma unroll
        for (int it=0; it<2; ++it){
            int i = tid + it*256;
            int r = i >> 3, c = (i & 7)*8;
            int lk = r;
            kr[it] = (lk < L_) ? *(const int4*)(qkv + (rowbase+lk)*3072 + 1024 + h*64 + c)
                               : (int4){0,0,0,0};
            vr[it] = *(const int4*)(Vt + ((size_t)bh*64 + r)*LP_ + c);
        }
    }

    for (int kt = 0; kt < nkt; ++kt) {
        __syncthreads();
        #pragma unroll
        for (int it=0; it<2; ++it){
            int i = tid + it*256;
            int r = i >> 3, c = (i & 7)*8;
            *(int4*)(&sK[r*72 + c]) = kr[it];
            *(int4*)(&sV[r*72 + c]) = vr[it];
        }
        __syncthreads();
        if (kt+1 < nkt){
            #pragma unroll
            for (int it=0; it<2; ++it){
                int i = tid + it*256;
                int r = i >> 3, c = (i & 7)*8;
                int lk = (kt+1)*64 + r;
                kr[it] = (lk < L_) ? *(const int4*)(qkv + (rowbase+lk)*3072 + 1024 + h*64 + c)
                                   : (int4){0,0,0,0};
                int vc = (kt+1)*64 + c;
                vr[it] = (vc + 8 <= LP_) ? *(const int4*)(Vt + ((size_t)bh*64 + r)*LP_ + vc)
                                         : (int4){0,0,0,0};
            }
        }

        bool full = (kt != 32);
        {
            bf16x8 kf[4][2];
            #pragma unroll
            for (int ki=0;ki<4;++ki)
                #pragma unroll
                for (int s=0;s<2;++s)
                    kf[ki][s] = *(const bf16x8*)(&sK[(ki*16+lrow)*72 + s*32 + lk8]);
            #pragma unroll
            for (int ki=0;ki<4;++ki){
                #pragma unroll
                for (int qi=0;qi<2;++qi){
                    f32x4 t = {};
                    t = MFMA(kf[ki][0], qf[qi][0], t);
                    t = MFMA(kf[ki][1], qf[qi][1], t);
                    float p[4];
                    #pragma unroll
                    for (int r=0;r<4;++r){
                        float e = __builtin_amdgcn_exp2f(t[r]*QSC);
                        p[r] = (full || (2048 + ki*16 + quad*4 + r) < L_) ? e : 0.f;
                        lst[qi] += p[r];
                    }
                    union { int2 d2; __hip_bfloat162 h2[2]; } u;
                    u.h2[0] = __float22bfloat162_rn({p[0], p[1]});
                    u.h2[1] = __float22bfloat162_rn({p[2], p[3]});
                    *(int2*)(&pw[(qi*16 + lrow)*72 + ki*16 + quad*4]) = u.d2;
                }
            }
        }

        bf16x8 vf[4][2];
        #pragma unroll
        for (int ni=0;ni<4;++ni)
            #pragma unroll
            for (int s=0;s<2;++s)
                vf[ni][s] = *(const bf16x8*)(&sV[(ni*16+lrow)*72 + s*32 + lk8]);
        bf16x8 pf[2][2];
        #pragma unroll
        for (int mi=0;mi<2;++mi)
            #pragma unroll
            for (int s=0;s<2;++s)
                pf[mi][s] = *(const bf16x8*)(&pw[(mi*16 + lrow)*72 + s*32 + quad*8]);
        #pragma unroll
        for (int mi=0;mi<2;++mi)
            #pragma unroll
            for (int ni=0;ni<4;++ni){
                f32x4 t = o_[mi][ni];
                t = MFMA(pf[mi][0], vf[ni][0], t);
                t = MFMA(pf[mi][1], vf[ni][1], t);
                o_[mi][ni] = t;
            }
    }

    #pragma unroll
    for (int qi=0;qi<2;++qi){
        lst[qi] += __shfl_xor(lst[qi], 16);
        lst[qi] += __shfl_xor(lst[qi], 32);
    }

    #pragma unroll
    for (int mi=0;mi<2;++mi)
        #pragma unroll
        for (int r=0;r<4;++r){
            float sum = __shfl(lst[mi], quad*4 + r);
            float inv = 1.f / sum;
            int lq = q0 + wave*32 + mi*16 + quad*4 + r;
            if (lq < L_){
                size_t base = (rowbase + lq)*1024 + h*64;
                #pragma unroll
                for (int ni=0;ni<4;++ni)
                    out[base + ni*16 + lrow] = o_[mi][ni][r]*inv;
            }
        }
}

// ---------------- LayerNorm (fp32 in) -> bf16 ----------------
__global__ __launch_bounds__(256)
void ln_kernel(const float* __restrict__ in, const float* __restrict__ gamma,
               const float* __restrict__ beta, bf16* __restrict__ y)
{
    int row = blockIdx.x;
    int tid = threadIdx.x;
    int wave = tid >> 6, lane = tid & 63;
    float4 v4 = *(const float4*)(in + (size_t)row*1024 + tid*4);
    float v[4] = {v4.x, v4.y, v4.z, v4.w};
    float s = 0.f, q = 0.f;
    #pragma unroll
    for (int j=0;j<4;++j){ s += v[j]; q += v[j]*v[j]; }
    #pragma unroll
    for (int o=1;o<64;o<<=1){ s += __shfl_xor(s, o); q += __shfl_xor(q, o); }
    __shared__ float sh[8];
    if (lane == 0){ sh[wave] = s; sh[4+wave] = q; }
    __syncthreads();
    s = sh[0]+sh[1]+sh[2]+sh[3];
    q = sh[4]+sh[5]+sh[6]+sh[7];
    float mu  = s * (1.f/1024.f);
    float var = q * (1.f/1024.f) - mu*mu;
    float rstd = rsqrtf(var + 1e-5f);
    int2 raw;
    bf16* ob = (bf16*)&raw;
    #pragma unroll
    for (int j=0;j<4;++j){
        float g = gamma[tid*4+j], be = beta[tid*4+j];
        ob[j] = f2b((v[j]-mu)*rstd*g + be);
    }
    *(int2*)(y + (size_t)row*1024 + tid*4) = raw;
}

// ---------------- launch ----------------
extern "C" void kernel_launch(void* const* d_in, const int* in_sizes, int n_in,
                              void* d_out, int out_size, void* d_ws, size_t ws_size,
                              hipStream_t stream)
{
    const float* x     = (const float*)d_in[0];
    const float* rope  = (const float*)d_in[1];
    const float* Wqkv  = (const float*)d_in[2];
    const float* bqkv  = (const float*)d_in[3];
    const float* Wproj = (const float*)d_in[4];
    const float* bproj = (const float*)d_in[5];
    const float* lng   = (const float*)d_in[6];
    const float* lnb   = (const float*)d_in[7];
    float* out = (float*)d_out;

    char* ws = (char*)d_ws;
    size_t off = 0;
    auto alloc = [&](size_t bytes)->char* {
        char* p = ws + off;
        off += (bytes + 255) & ~(size_t)255;
        return p;
    };
    bf16* xhi    = (bf16*)alloc((size_t)M_*C_*2);
    bf16* xlo    = (bf16*)alloc((size_t)M_*C_*2);
    bf16* WqkvT  = (bf16*)alloc((size_t)3*C_*C_*2);
    bf16* WprojT = (bf16*)alloc((size_t)C_*C_*2);
    bf16* qkv    = (bf16*)alloc((size_t)M_*3*C_*2);
    bf16* Vt     = (bf16*)alloc((size_t)B_*H_*D_*LP_*2);

    float* attnF = (float*)xhi;        // xhi+xlo region = exactly M*C*4 bytes
    bf16*  y     = qkv;                // qkv dead after attention

    cvt_split<<<M_*C_/1024, 256, 0, stream>>>(x, xhi, xlo, M_*C_);
    transpose_cvt<<<dim3(3*C_/32, C_/32), dim3(32,8), 0, stream>>>(Wqkv, WqkvT, C_, 3*C_);
    transpose_cvt<<<dim3(C_/32, C_/32), dim3(32,8), 0, stream>>>(Wproj, WprojT, C_, C_);
    gemm_wide<bf16, true><<<dim3(3*C_/256, (M_+127)/128), 256, 0, stream>>>(
        xhi, xlo, WqkvT, bqkv, qkv, M_, 3*C_, C_);
    rope_kernel<<<(M_*H_*32)/256, 256, 0, stream>>>(qkv, rope);
    transpose_v<<<dim3((L_+63)/64, B_*H_), 256, 0, stream>>>(qkv, Vt);
    attn_kernel<<<dim3((L_+127)/128, B_*H_), 256, 0, stream>>>(qkv, Vt, attnF);
    ln_kernel<<<M_, 256, 0, stream>>>(attnF, lng, lnb, y);
    gemm_wide<float, false><<<dim3(C_/256, (M_+127)/128), 256, 0, stream>>>(
        y, nullptr, WprojT, bproj, out, M_, C_, C_);
}